// Round 12
// baseline (434.595 us; speedup 1.0000x reference)
//
#include <hip/hip_runtime.h>
#include <hip/hip_cooperative_groups.h>

namespace cg = cooperative_groups;

// GCN VGAE encoder, pull-based. N=50000 (<2^16), E=1.6M.
// out[i] = dis[i]*(hs[i]+sum_{j->i} hs[j]), hs = dis.*(x@W)
// Round 12: front half (bcur-init -> tilesort -> build -> gemm1) fused into ONE
// cooperative kernel (grid.sync between phases); hist/scanb eliminated via
// fixed-capacity buckets (CAP=16384/bucket, mean 8163) with per-node int2
// extents rp2[node]={beg,end} (gapped CSR). 9 dispatches -> 4: inter-dispatch
// overhead measured ~7us each (rounds 9-11).
// Pulls: bf16 slabs of 32ch, XCD-pinned merged dispatches (round 11).
// Bounded unrolls (round 7: full unroll spilled). No hipMemsetAsync (round 10).

#define NBMAX 256
#define NTILE 512
#define CAPSH 14
#define CAP (1 << CAPSH)

__device__ __forceinline__ ushort f2bf(float x) {            // RNE fp32->bf16
    unsigned u = __float_as_uint(x);
    u = (u + 0x7FFFu + ((u >> 16) & 1u)) >> 16;
    return (ushort)u;
}
__device__ __forceinline__ float bflo(unsigned u) { return __uint_as_float(u << 16); }
__device__ __forceinline__ float bfhi(unsigned u) { return __uint_as_float(u & 0xFFFF0000u); }

__device__ __forceinline__ void acc8(float* a, uint4 x) {    // a[0..7] += 8 bf16
    a[0] += bflo(x.x); a[1] += bfhi(x.x);
    a[2] += bflo(x.y); a[3] += bfhi(x.y);
    a[4] += bflo(x.z); a[5] += bfhi(x.z);
    a[6] += bflo(x.w); a[7] += bfhi(x.w);
}

// Cooperative front: bcur init -> tilesort -> build(rp2,dis,csr) -> gemm1(hs1b)
__global__ __launch_bounds__(256) void k_front(const int* __restrict__ row,
                                               const int* __restrict__ col,
                                               const float* __restrict__ x,
                                               const float* __restrict__ W1,
                                               int* __restrict__ bcur,
                                               int* __restrict__ binbuf,
                                               int* __restrict__ rp2,
                                               float* __restrict__ dis,
                                               ushort* __restrict__ csr,
                                               ushort* __restrict__ hs1b,
                                               int n, int e, int nb, int ntiles) {
    __shared__ __align__(16) unsigned char smem[40960];
    cg::grid_group grid = cg::this_grid();
    int t = threadIdx.x;

    // ph0: bucket cursors at fixed bases
    for (int i = blockIdx.x * 256 + t; i < nb; i += gridDim.x * 256)
        bcur[i] = i << CAPSH;
    grid.sync();

    // ph1: tilesort into fixed-cap bucket regions (packed row | lcol<<16)
    {
        int* lh = (int*)smem;
        int chunk = (e + NTILE - 1) / NTILE;
        for (int tile = blockIdx.x; tile < NTILE; tile += gridDim.x) {
            __syncthreads();
            for (int i = t; i < NBMAX; i += 256) lh[i] = 0;
            __syncthreads();
            int t0 = tile * chunk;
            int t1 = t0 + chunk < e ? t0 + chunk : e;
            for (int i = t0 + t; i < t1; i += 256)
                atomicAdd(&lh[col[i] >> 8], 1);
            __syncthreads();
            for (int b = t; b < NBMAX; b += 256) {
                int c = lh[b];
                if (c) lh[b] = atomicAdd(bcur + b, c);
            }
            __syncthreads();
            for (int i = t0 + t; i < t1; i += 256) {
                int c = col[i];
                int pos = atomicAdd(&lh[c >> 8], 1);
                if (pos < (((c >> 8) + 1) << CAPSH))     // overflow guard
                    binbuf[pos] = row[i] | ((c & 255) << 16);
            }
        }
    }
    grid.sync();

    // ph2: build per bucket: counts -> prefix -> rp2/dis, scatter csr
    {
        int* lcnt = (int*)smem;
        int* s    = lcnt + 256;
        int* cur  = s + 256;
        for (int b = blockIdx.x; b < nb; b += gridDim.x) {
            __syncthreads();
            lcnt[t] = 0;
            __syncthreads();
            int lo = b << CAPSH;
            int hi = bcur[b];
            int cap = (b + 1) << CAPSH;
            if (hi > cap) hi = cap;
            for (int k = lo + t; k < hi; k += 256)
                atomicAdd(&lcnt[(binbuf[k] >> 16) & 255], 1);
            __syncthreads();
            int v = lcnt[t];
            s[t] = v;
            __syncthreads();
            for (int off = 1; off < 256; off <<= 1) {
                int u = (t >= off) ? s[t - off] : 0;
                __syncthreads();
                s[t] += u;
                __syncthreads();
            }
            int node0 = b << 8;
            int nloc = n - node0 < 256 ? n - node0 : 256;
            if (t < nloc) {
                int beg = lo + s[t] - v;
                rp2[2 * (node0 + t)] = beg;
                rp2[2 * (node0 + t) + 1] = beg + v;
                cur[t] = beg;
                dis[node0 + t] = rsqrtf((float)v + 1.0f);
            }
            __syncthreads();
            for (int k = lo + t; k < hi; k += 256) {
                int p = binbuf[k];
                int pos = atomicAdd(&cur[(p >> 16) & 255], 1);
                csr[pos] = (ushort)(p & 0xffff);
            }
        }
    }
    grid.sync();

    // ph3: gemm1: x[n,128]@W1[128,64]*dis -> bf16 slabs hs1b[2][n][32]
    {
        float4 (*w4)[64]    = reinterpret_cast<float4(*)[64]>(smem);          // 32KB
        float4 (*xs)[16][8] = reinterpret_cast<float4(*)[16][8]>(smem + 32768); // 8KB
        __syncthreads();
        for (int i = t; i < 128 * 64; i += 256) {
            int k = i >> 6, c = i & 63;
            ((float*)&w4[k >> 2][c])[k & 3] = W1[i];
        }
        __syncthreads();
        int wid = t >> 6;
        int lane = t & 63;
        const float4* x4 = (const float4*)x;
        for (int tile = blockIdx.x; tile < ntiles; tile += gridDim.x) {
            int r0 = tile * 64 + wid * 16;
            float acc[16];
#pragma unroll
            for (int r = 0; r < 16; ++r) acc[r] = 0.f;
#pragma unroll
            for (int st = 0; st < 4; ++st) {
#pragma unroll
                for (int j = 0; j < 2; ++j) {
                    int idx = j * 64 + lane;   // (rowl, k4l) = (idx>>3, idx&7)
                    int rr = r0 + (idx >> 3);
                    if (rr >= n) rr = n - 1;
                    xs[wid][idx >> 3][idx & 7] = x4[(size_t)rr * 32 + st * 8 + (idx & 7)];
                }
                // xs[wid] is wave-private: in-wave lgkmcnt ordering suffices
#pragma unroll 2
                for (int k4 = 0; k4 < 8; ++k4) {
                    float4 wv = w4[st * 8 + k4][lane];
#pragma unroll
                    for (int r = 0; r < 16; ++r) {
                        float4 xv = xs[wid][r][k4];
                        acc[r] = fmaf(xv.x, wv.x, acc[r]);
                        acc[r] = fmaf(xv.y, wv.y, acc[r]);
                        acc[r] = fmaf(xv.z, wv.z, acc[r]);
                        acc[r] = fmaf(xv.w, wv.w, acc[r]);
                    }
                }
            }
            ushort* hb = hs1b + (size_t)(lane >> 5) * n * 32 + (lane & 31);
#pragma unroll
            for (int r = 0; r < 16; ++r) {
                int rw = r0 + r;
                if (rw < n) hb[(size_t)rw * 32] = f2bf(dis[rw] * acc[r]);
            }
        }
    }
}

// pull1, both slabs in one dispatch; xcd=bid&7 picks slab (xcd>>2) so each
// XCD's L2 caches one 3.2MB slab. 4 lanes/node, uint4 (8 bf16)/lane.
__global__ __launch_bounds__(256) void k_pull1(const int* __restrict__ rp2,
                                               const ushort* __restrict__ csr,
                                               const ushort* __restrict__ hs1b,
                                               const float* __restrict__ dis,
                                               const float* __restrict__ b1,
                                               ushort* __restrict__ hs2b, int n) {
    int xcd = blockIdx.x & 7;
    int sid = xcd >> 2;
    int idx = (blockIdx.x >> 3) * 4 + (xcd & 3);
    int node = idx * 64 + (threadIdx.x >> 2);
    int c4 = threadIdx.x & 3;
    if (node >= n) return;
    size_t slab = (size_t)sid * n * 32;
    const uint4* h4 = (const uint4*)(hs1b + slab);
    int2 be = ((const int2*)rp2)[node];
    float a[8], b[8];
    uint4 v = h4[(size_t)node * 4 + c4];
    a[0] = bflo(v.x); a[1] = bfhi(v.x); a[2] = bflo(v.y); a[3] = bfhi(v.y);
    a[4] = bflo(v.z); a[5] = bfhi(v.z); a[6] = bflo(v.w); a[7] = bfhi(v.w);
#pragma unroll
    for (int j = 0; j < 8; ++j) b[j] = 0.f;
    int k = be.x;
    for (; k + 4 <= be.y; k += 4) {
        uint4 v0 = h4[(size_t)csr[k] * 4 + c4];
        uint4 v1 = h4[(size_t)csr[k + 1] * 4 + c4];
        uint4 v2 = h4[(size_t)csr[k + 2] * 4 + c4];
        uint4 v3 = h4[(size_t)csr[k + 3] * 4 + c4];
        acc8(a, v0); acc8(b, v1); acc8(a, v2); acc8(b, v3);
    }
    for (; k < be.y; ++k) acc8(a, h4[(size_t)csr[k] * 4 + c4]);
    float d = dis[node];
    const float* b1s = b1 + sid * 32;
    float4 bb0 = *(const float4*)(b1s + c4 * 8);
    float4 bb1 = *(const float4*)(b1s + c4 * 8 + 4);
    float bj[8] = {bb0.x, bb0.y, bb0.z, bb0.w, bb1.x, bb1.y, bb1.z, bb1.w};
    float o[8];
#pragma unroll
    for (int j = 0; j < 8; ++j) {
        float tt = fmaf(d, a[j] + b[j], bj[j]);
        o[j] = tt > 0.f ? d * tt : 0.f;
    }
    uint4 w;
    w.x = (unsigned)f2bf(o[0]) | ((unsigned)f2bf(o[1]) << 16);
    w.y = (unsigned)f2bf(o[2]) | ((unsigned)f2bf(o[3]) << 16);
    w.z = (unsigned)f2bf(o[4]) | ((unsigned)f2bf(o[5]) << 16);
    w.w = (unsigned)f2bf(o[6]) | ((unsigned)f2bf(o[7]) << 16);
    ((uint4*)(hs2b + slab))[(size_t)node * 4 + c4] = w;
}

// pull2, both slabs in one dispatch (same XCD-pinned mapping). fp32 out.
__global__ __launch_bounds__(256) void k_pull2(const int* __restrict__ rp2,
                                               const ushort* __restrict__ csr,
                                               const ushort* __restrict__ hs2b,
                                               const float* __restrict__ dis,
                                               float* __restrict__ gagg, int n) {
    int xcd = blockIdx.x & 7;
    int sid = xcd >> 2;
    int idx = (blockIdx.x >> 3) * 4 + (xcd & 3);
    int node = idx * 64 + (threadIdx.x >> 2);
    int c4 = threadIdx.x & 3;
    if (node >= n) return;
    const uint4* h4 = (const uint4*)(hs2b + (size_t)sid * n * 32);
    int2 be = ((const int2*)rp2)[node];
    float a[8], b[8];
    uint4 v = h4[(size_t)node * 4 + c4];
    a[0] = bflo(v.x); a[1] = bfhi(v.x); a[2] = bflo(v.y); a[3] = bfhi(v.y);
    a[4] = bflo(v.z); a[5] = bfhi(v.z); a[6] = bflo(v.w); a[7] = bfhi(v.w);
#pragma unroll
    for (int j = 0; j < 8; ++j) b[j] = 0.f;
    int k = be.x;
    for (; k + 4 <= be.y; k += 4) {
        uint4 v0 = h4[(size_t)csr[k] * 4 + c4];
        uint4 v1 = h4[(size_t)csr[k + 1] * 4 + c4];
        uint4 v2 = h4[(size_t)csr[k + 2] * 4 + c4];
        uint4 v3 = h4[(size_t)csr[k + 3] * 4 + c4];
        acc8(a, v0); acc8(b, v1); acc8(a, v2); acc8(b, v3);
    }
    for (; k < be.y; ++k) acc8(a, h4[(size_t)csr[k] * 4 + c4]);
    float d = dis[node];
    float* dst = gagg + (size_t)node * 64 + sid * 32 + c4 * 8;
    *(float4*)dst = make_float4(d * (a[0] + b[0]), d * (a[1] + b[1]),
                                d * (a[2] + b[2]), d * (a[3] + b[3]));
    *(float4*)(dst + 4) = make_float4(d * (a[4] + b[4]), d * (a[5] + b[5]),
                                      d * (a[6] + b[6]), d * (a[7] + b[7]));
}

// g[n,64] @ {W2,W3}[64,32] + bias -> out = mu ++ logvar. 64 rows/block.
__global__ __launch_bounds__(256) void k_gemm23(const float* __restrict__ g,
                                                const float* __restrict__ W2,
                                                const float* __restrict__ b2,
                                                const float* __restrict__ W3,
                                                const float* __restrict__ b3,
                                                float* __restrict__ out, int n) {
    __shared__ float ws[2 * 32 * 17 * 4];  // [half][ch][k4] float4, stride 17
    __shared__ float4 gs[4][16 * 16];      // per-wave 16 rows x 16 float4
    for (int i = threadIdx.x; i < 64 * 32; i += 256) {
        int k = i >> 5, c = i & 31;
        int a = (c * 17 + (k >> 2)) * 4 + (k & 3);
        ws[a] = W2[i];
        ws[2176 + a] = W3[i];
    }
    int wid = threadIdx.x >> 6;
    int lane = threadIdx.x & 63;
    int half = lane >> 5;
    int ch = lane & 31;
    int r0 = blockIdx.x * 64 + wid * 16;
    const float4* g4 = (const float4*)g;
#pragma unroll
    for (int j = 0; j < 4; ++j) {
        int idx = j * 64 + lane;           // (row, k4) = (idx>>4, idx&15)
        int rr = r0 + (idx >> 4);
        if (rr >= n) rr = n - 1;
        gs[wid][idx] = g4[(size_t)rr * 16 + (idx & 15)];
    }
    __syncthreads();
    float acc[16];
#pragma unroll
    for (int r = 0; r < 16; ++r) acc[r] = 0.f;
    const float4* wl = (const float4*)ws;
    const float4* gw = gs[wid];
#pragma unroll 2
    for (int k4 = 0; k4 < 16; ++k4) {
        float4 wv = wl[half * 544 + ch * 17 + k4];
#pragma unroll
        for (int r = 0; r < 16; ++r) {
            float4 gv = gw[r * 16 + k4];   // wave-uniform -> LDS broadcast
            acc[r] = fmaf(gv.x, wv.x, acc[r]);
            acc[r] = fmaf(gv.y, wv.y, acc[r]);
            acc[r] = fmaf(gv.z, wv.z, acc[r]);
            acc[r] = fmaf(gv.w, wv.w, acc[r]);
        }
    }
    float bb = half ? b3[ch] : b2[ch];
    size_t obase = half ? (size_t)n * 32 : 0;
#pragma unroll
    for (int r = 0; r < 16; ++r) {
        int rw = r0 + r;
        if (rw < n) out[obase + (size_t)rw * 32 + ch] = acc[r] + bb;
    }
}

extern "C" void kernel_launch(void* const* d_in, const int* in_sizes, int n_in,
                              void* d_out, int out_size, void* d_ws, size_t ws_size,
                              hipStream_t stream) {
    const float* x  = (const float*)d_in[0];
    const int*   ei = (const int*)d_in[1];
    const float* W1 = (const float*)d_in[2];
    const float* b1 = (const float*)d_in[3];
    const float* W2 = (const float*)d_in[4];
    const float* b2 = (const float*)d_in[5];
    const float* W3 = (const float*)d_in[6];
    const float* b3 = (const float*)d_in[7];

    int n = in_sizes[0] / 128;   // 50000
    int e = in_sizes[1] / 2;     // 1600000
    int nb = (n + 255) >> 8;     // 196 buckets of 256 nodes
    const int* row = ei;
    const int* col = ei + e;

    // workspace layout (bytes, n=50000/nb=196): dis 0.2M | hs1b 6.4M | hs2b 6.4M
    // | bcur ~0 | rp2 0.4M | csr 6.4M | gagg 12.8M (binbuf aliases gagg+tail)
    float* fws   = (float*)d_ws;
    float* dis   = fws;                                   // n fp32
    ushort* hs1b = (ushort*)(fws + n);                    // 2 slabs x n x 32 bf16
    ushort* hs2b = hs1b + (size_t)2 * n * 32;             // 2 slabs x n x 32 bf16
    int* bcur    = (int*)(hs2b + (size_t)2 * n * 32);     // nb
    int* rp2     = bcur + ((nb + 1) & ~1);                // 2n ints (int2/node)
    ushort* csr  = (ushort*)(rp2 + 2 * (size_t)n);        // nb*CAP ushorts
    float* gagg  = (float*)(csr + (size_t)nb * CAP);      // n*64 fp32
    int* binbuf  = (int*)gagg;                            // nb*CAP ints (dead before pull2)
    float* out   = (float*)d_out;

    int ntiles = (n + 63) / 64;             // 782 gemm1 row-tiles
    int pg = ntiles;                        // node-blocks per slab
    int pgrid = 8 * ((pg + 3) / 4);         // XCD-pinned 2-slab grid

    // cooperative grid: 40KB LDS -> 4 blocks/CU expected; query to be safe
    int maxb = 0;
    if (hipOccupancyMaxActiveBlocksPerMultiprocessor(&maxb, k_front, 256, 0) != hipSuccess || maxb < 1)
        maxb = 2;
    int grid = maxb * 256;                  // 256 CUs (MI355X)
    if (grid > 1024) grid = 1024;

    void* kargs[] = {(void*)&row, (void*)&col, (void*)&x, (void*)&W1,
                     (void*)&bcur, (void*)&binbuf, (void*)&rp2, (void*)&dis,
                     (void*)&csr, (void*)&hs1b, (void*)&n, (void*)&e,
                     (void*)&nb, (void*)&ntiles};
    hipLaunchCooperativeKernel((void*)k_front, dim3(grid), dim3(256), kargs, 0, stream);

    dim3 blk(256);
    k_pull1<<<pgrid, blk, 0, stream>>>(rp2, csr, hs1b, dis, b1, hs2b, n);
    k_pull2<<<pgrid, blk, 0, stream>>>(rp2, csr, hs2b, dis, gagg, n);
    k_gemm23<<<(n + 63) / 64, blk, 0, stream>>>(gagg, W2, b2, W3, b3, out, n);
}

// Round 13
// 158.990 us; speedup vs baseline: 2.7335x; 2.7335x over previous
//
#include <hip/hip_runtime.h>

// GCN VGAE encoder, pull-based. N=50000 (<2^16), E=1.6M.
// out[i] = dis[i]*(hs[i]+sum_{j->i} hs[j]), hs = dis.*(x@W)
// Round 13: separate dispatches again (round 12: grid.sync() ~100us each on
// MI355X — cooperative fusion regressed 178->434us). Kept from round 12:
// fixed-capacity buckets (CAP=16384/bucket, mean 8163) + gapped CSR with
// per-node int2 extents rp2 -> no hist/scanb. 7 dispatches.
// Pulls: bf16 slabs of 32ch, XCD-pinned merged dispatches (round 11).
// Bounded unrolls (round 7: full unroll spilled). No hipMemsetAsync (round 10:
// graph-captured fill node ~40us/replay).

#define NBMAX 256
#define NTILE 512
#define CAPSH 14
#define CAP (1 << CAPSH)

__device__ __forceinline__ ushort f2bf(float x) {            // RNE fp32->bf16
    unsigned u = __float_as_uint(x);
    u = (u + 0x7FFFu + ((u >> 16) & 1u)) >> 16;
    return (ushort)u;
}
__device__ __forceinline__ float bflo(unsigned u) { return __uint_as_float(u << 16); }
__device__ __forceinline__ float bfhi(unsigned u) { return __uint_as_float(u & 0xFFFF0000u); }

__device__ __forceinline__ void acc8(float* a, uint4 x) {    // a[0..7] += 8 bf16
    a[0] += bflo(x.x); a[1] += bfhi(x.x);
    a[2] += bflo(x.y); a[3] += bfhi(x.y);
    a[4] += bflo(x.z); a[5] += bfhi(x.z);
    a[6] += bflo(x.w); a[7] += bfhi(x.w);
}

__global__ void k_init(int* __restrict__ bcur, int nb) {
    int i = blockIdx.x * 256 + threadIdx.x;
    if (i < nb) bcur[i] = i << CAPSH;
}

// tilesort into fixed-cap bucket regions (packed row | lcol<<16)
__global__ __launch_bounds__(256) void k_tilesort(const int* __restrict__ row,
                                                  const int* __restrict__ col,
                                                  int* __restrict__ bcur,
                                                  int* __restrict__ binbuf,
                                                  int e, int chunk) {
    __shared__ int lh[NBMAX];
    int t0 = blockIdx.x * chunk;
    int t1 = t0 + chunk < e ? t0 + chunk : e;
    for (int i = threadIdx.x; i < NBMAX; i += 256) lh[i] = 0;
    __syncthreads();
    for (int i = t0 + threadIdx.x; i < t1; i += 256)
        atomicAdd(&lh[col[i] >> 8], 1);
    __syncthreads();
    for (int b = threadIdx.x; b < NBMAX; b += 256) {
        int c = lh[b];
        if (c) lh[b] = atomicAdd(bcur + b, c);
    }
    __syncthreads();
    for (int i = t0 + threadIdx.x; i < t1; i += 256) {
        int c = col[i];
        int pos = atomicAdd(&lh[c >> 8], 1);
        if (pos < (((c >> 8) + 1) << CAPSH))      // overflow guard (90 sigma)
            binbuf[pos] = row[i] | ((c & 255) << 16);
    }
}

// per bucket: counts -> prefix -> rp2/dis, scatter csr (gapped CSR)
__global__ __launch_bounds__(256) void k_build(const int* __restrict__ binbuf,
                                               const int* __restrict__ bcur,
                                               float* __restrict__ dis,
                                               int* __restrict__ rp2,
                                               ushort* __restrict__ csr, int n) {
    __shared__ int lcnt[256], s[256], cur[256];
    int b = blockIdx.x;
    int t = threadIdx.x;
    int lo = b << CAPSH;
    int hi = bcur[b];
    int cap = (b + 1) << CAPSH;
    if (hi > cap) hi = cap;
    int node0 = b << 8;
    int nloc = n - node0 < 256 ? n - node0 : 256;
    lcnt[t] = 0;
    __syncthreads();
    for (int k = lo + t; k < hi; k += 256)
        atomicAdd(&lcnt[(binbuf[k] >> 16) & 255], 1);
    __syncthreads();
    int v = lcnt[t];
    s[t] = v;
    __syncthreads();
    for (int off = 1; off < 256; off <<= 1) {
        int u = (t >= off) ? s[t - off] : 0;
        __syncthreads();
        s[t] += u;
        __syncthreads();
    }
    if (t < nloc) {
        int beg = lo + s[t] - v;
        rp2[2 * (node0 + t)] = beg;
        rp2[2 * (node0 + t) + 1] = beg + v;
        cur[t] = beg;
        dis[node0 + t] = rsqrtf((float)v + 1.0f);
    }
    __syncthreads();
    for (int k = lo + t; k < hi; k += 256) {
        int p = binbuf[k];
        int pos = atomicAdd(&cur[(p >> 16) & 255], 1);
        csr[pos] = (ushort)(p & 0xffff);
    }
}

// x[n,128] @ W[128,64] * dis -> bf16 slabs hs1b[2][n][32]. 64 rows/block.
// W in LDS as [k4][ch] float4 (32KB); x staged per wave in 4 K-stages (8KB).
__global__ __launch_bounds__(256) void k_gemm1(const float* __restrict__ x,
                                               const float* __restrict__ W,
                                               const float* __restrict__ dis,
                                               ushort* __restrict__ hs1b, int n) {
    __shared__ float4 w4[32][64];          // [k4][ch]
    __shared__ float4 xs[4][16][8];        // [wave][row][k4local]
    for (int i = threadIdx.x; i < 128 * 64; i += 256) {
        int k = i >> 6, c = i & 63;
        ((float*)&w4[k >> 2][c])[k & 3] = W[i];
    }
    int wid = threadIdx.x >> 6;
    int lane = threadIdx.x & 63;
    int r0 = blockIdx.x * 64 + wid * 16;
    const float4* x4 = (const float4*)x;
    float acc[16];
#pragma unroll
    for (int r = 0; r < 16; ++r) acc[r] = 0.f;
    __syncthreads();
#pragma unroll
    for (int st = 0; st < 4; ++st) {
#pragma unroll
        for (int j = 0; j < 2; ++j) {
            int idx = j * 64 + lane;       // (rowl, k4l) = (idx>>3, idx&7)
            int rr = r0 + (idx >> 3);
            if (rr >= n) rr = n - 1;
            xs[wid][idx >> 3][idx & 7] = x4[(size_t)rr * 32 + st * 8 + (idx & 7)];
        }
        // xs[wid] is wave-private: in-wave lgkmcnt ordering suffices
#pragma unroll 2
        for (int k4 = 0; k4 < 8; ++k4) {
            float4 wv = w4[st * 8 + k4][lane];
#pragma unroll
            for (int r = 0; r < 16; ++r) {
                float4 xv = xs[wid][r][k4];
                acc[r] = fmaf(xv.x, wv.x, acc[r]);
                acc[r] = fmaf(xv.y, wv.y, acc[r]);
                acc[r] = fmaf(xv.z, wv.z, acc[r]);
                acc[r] = fmaf(xv.w, wv.w, acc[r]);
            }
        }
    }
    ushort* hb = hs1b + (size_t)(lane >> 5) * n * 32 + (lane & 31);
#pragma unroll
    for (int r = 0; r < 16; ++r) {
        int rw = r0 + r;
        if (rw < n) hb[(size_t)rw * 32] = f2bf(dis[rw] * acc[r]);
    }
}

// pull1, both slabs in one dispatch; xcd=bid&7 picks slab (xcd>>2) so each
// XCD's L2 caches one 3.2MB slab. 4 lanes/node, uint4 (8 bf16)/lane.
__global__ __launch_bounds__(256) void k_pull1(const int* __restrict__ rp2,
                                               const ushort* __restrict__ csr,
                                               const ushort* __restrict__ hs1b,
                                               const float* __restrict__ dis,
                                               const float* __restrict__ b1,
                                               ushort* __restrict__ hs2b, int n) {
    int xcd = blockIdx.x & 7;
    int sid = xcd >> 2;
    int idx = (blockIdx.x >> 3) * 4 + (xcd & 3);
    int node = idx * 64 + (threadIdx.x >> 2);
    int c4 = threadIdx.x & 3;
    if (node >= n) return;
    size_t slab = (size_t)sid * n * 32;
    const uint4* h4 = (const uint4*)(hs1b + slab);
    int2 be = ((const int2*)rp2)[node];
    float a[8], b[8];
    uint4 v = h4[(size_t)node * 4 + c4];
    a[0] = bflo(v.x); a[1] = bfhi(v.x); a[2] = bflo(v.y); a[3] = bfhi(v.y);
    a[4] = bflo(v.z); a[5] = bfhi(v.z); a[6] = bflo(v.w); a[7] = bfhi(v.w);
#pragma unroll
    for (int j = 0; j < 8; ++j) b[j] = 0.f;
    int k = be.x;
    for (; k + 4 <= be.y; k += 4) {
        uint4 v0 = h4[(size_t)csr[k] * 4 + c4];
        uint4 v1 = h4[(size_t)csr[k + 1] * 4 + c4];
        uint4 v2 = h4[(size_t)csr[k + 2] * 4 + c4];
        uint4 v3 = h4[(size_t)csr[k + 3] * 4 + c4];
        acc8(a, v0); acc8(b, v1); acc8(a, v2); acc8(b, v3);
    }
    for (; k < be.y; ++k) acc8(a, h4[(size_t)csr[k] * 4 + c4]);
    float d = dis[node];
    const float* b1s = b1 + sid * 32;
    float4 bb0 = *(const float4*)(b1s + c4 * 8);
    float4 bb1 = *(const float4*)(b1s + c4 * 8 + 4);
    float bj[8] = {bb0.x, bb0.y, bb0.z, bb0.w, bb1.x, bb1.y, bb1.z, bb1.w};
    float o[8];
#pragma unroll
    for (int j = 0; j < 8; ++j) {
        float tt = fmaf(d, a[j] + b[j], bj[j]);
        o[j] = tt > 0.f ? d * tt : 0.f;
    }
    uint4 w;
    w.x = (unsigned)f2bf(o[0]) | ((unsigned)f2bf(o[1]) << 16);
    w.y = (unsigned)f2bf(o[2]) | ((unsigned)f2bf(o[3]) << 16);
    w.z = (unsigned)f2bf(o[4]) | ((unsigned)f2bf(o[5]) << 16);
    w.w = (unsigned)f2bf(o[6]) | ((unsigned)f2bf(o[7]) << 16);
    ((uint4*)(hs2b + slab))[(size_t)node * 4 + c4] = w;
}

// pull2, both slabs in one dispatch (same XCD-pinned mapping). fp32 out.
__global__ __launch_bounds__(256) void k_pull2(const int* __restrict__ rp2,
                                               const ushort* __restrict__ csr,
                                               const ushort* __restrict__ hs2b,
                                               const float* __restrict__ dis,
                                               float* __restrict__ gagg, int n) {
    int xcd = blockIdx.x & 7;
    int sid = xcd >> 2;
    int idx = (blockIdx.x >> 3) * 4 + (xcd & 3);
    int node = idx * 64 + (threadIdx.x >> 2);
    int c4 = threadIdx.x & 3;
    if (node >= n) return;
    const uint4* h4 = (const uint4*)(hs2b + (size_t)sid * n * 32);
    int2 be = ((const int2*)rp2)[node];
    float a[8], b[8];
    uint4 v = h4[(size_t)node * 4 + c4];
    a[0] = bflo(v.x); a[1] = bfhi(v.x); a[2] = bflo(v.y); a[3] = bfhi(v.y);
    a[4] = bflo(v.z); a[5] = bfhi(v.z); a[6] = bflo(v.w); a[7] = bfhi(v.w);
#pragma unroll
    for (int j = 0; j < 8; ++j) b[j] = 0.f;
    int k = be.x;
    for (; k + 4 <= be.y; k += 4) {
        uint4 v0 = h4[(size_t)csr[k] * 4 + c4];
        uint4 v1 = h4[(size_t)csr[k + 1] * 4 + c4];
        uint4 v2 = h4[(size_t)csr[k + 2] * 4 + c4];
        uint4 v3 = h4[(size_t)csr[k + 3] * 4 + c4];
        acc8(a, v0); acc8(b, v1); acc8(a, v2); acc8(b, v3);
    }
    for (; k < be.y; ++k) acc8(a, h4[(size_t)csr[k] * 4 + c4]);
    float d = dis[node];
    float* dst = gagg + (size_t)node * 64 + sid * 32 + c4 * 8;
    *(float4*)dst = make_float4(d * (a[0] + b[0]), d * (a[1] + b[1]),
                                d * (a[2] + b[2]), d * (a[3] + b[3]));
    *(float4*)(dst + 4) = make_float4(d * (a[4] + b[4]), d * (a[5] + b[5]),
                                      d * (a[6] + b[6]), d * (a[7] + b[7]));
}

// g[n,64] @ {W2,W3}[64,32] + bias -> out = mu ++ logvar. 64 rows/block.
__global__ __launch_bounds__(256) void k_gemm23(const float* __restrict__ g,
                                                const float* __restrict__ W2,
                                                const float* __restrict__ b2,
                                                const float* __restrict__ W3,
                                                const float* __restrict__ b3,
                                                float* __restrict__ out, int n) {
    __shared__ float ws[2 * 32 * 17 * 4];  // [half][ch][k4] float4, stride 17
    __shared__ float4 gs[4][16 * 16];      // per-wave 16 rows x 16 float4
    for (int i = threadIdx.x; i < 64 * 32; i += 256) {
        int k = i >> 5, c = i & 31;
        int a = (c * 17 + (k >> 2)) * 4 + (k & 3);
        ws[a] = W2[i];
        ws[2176 + a] = W3[i];
    }
    int wid = threadIdx.x >> 6;
    int lane = threadIdx.x & 63;
    int half = lane >> 5;
    int ch = lane & 31;
    int r0 = blockIdx.x * 64 + wid * 16;
    const float4* g4 = (const float4*)g;
#pragma unroll
    for (int j = 0; j < 4; ++j) {
        int idx = j * 64 + lane;           // (row, k4) = (idx>>4, idx&15)
        int rr = r0 + (idx >> 4);
        if (rr >= n) rr = n - 1;
        gs[wid][idx] = g4[(size_t)rr * 16 + (idx & 15)];
    }
    __syncthreads();
    float acc[16];
#pragma unroll
    for (int r = 0; r < 16; ++r) acc[r] = 0.f;
    const float4* wl = (const float4*)ws;
    const float4* gw = gs[wid];
#pragma unroll 2
    for (int k4 = 0; k4 < 16; ++k4) {
        float4 wv = wl[half * 544 + ch * 17 + k4];
#pragma unroll
        for (int r = 0; r < 16; ++r) {
            float4 gv = gw[r * 16 + k4];   // wave-uniform -> LDS broadcast
            acc[r] = fmaf(gv.x, wv.x, acc[r]);
            acc[r] = fmaf(gv.y, wv.y, acc[r]);
            acc[r] = fmaf(gv.z, wv.z, acc[r]);
            acc[r] = fmaf(gv.w, wv.w, acc[r]);
        }
    }
    float bb = half ? b3[ch] : b2[ch];
    size_t obase = half ? (size_t)n * 32 : 0;
#pragma unroll
    for (int r = 0; r < 16; ++r) {
        int rw = r0 + r;
        if (rw < n) out[obase + (size_t)rw * 32 + ch] = acc[r] + bb;
    }
}

extern "C" void kernel_launch(void* const* d_in, const int* in_sizes, int n_in,
                              void* d_out, int out_size, void* d_ws, size_t ws_size,
                              hipStream_t stream) {
    const float* x  = (const float*)d_in[0];
    const int*   ei = (const int*)d_in[1];
    const float* W1 = (const float*)d_in[2];
    const float* b1 = (const float*)d_in[3];
    const float* W2 = (const float*)d_in[4];
    const float* b2 = (const float*)d_in[5];
    const float* W3 = (const float*)d_in[6];
    const float* b3 = (const float*)d_in[7];

    int n = in_sizes[0] / 128;   // 50000
    int e = in_sizes[1] / 2;     // 1600000
    int nb = (n + 255) >> 8;     // 196 buckets of 256 nodes
    const int* row = ei;
    const int* col = ei + e;

    // ws layout: dis 0.2M | hs1b 6.4M | hs2b 6.4M | bcur | rp2 0.4M |
    // csr 6.4M | gagg 12.8M | binbuf 12.85M   (~45.5MB total)
    float* fws   = (float*)d_ws;
    float* dis   = fws;                                   // n fp32
    ushort* hs1b = (ushort*)(fws + n);                    // 2 slabs x n x 32 bf16
    ushort* hs2b = hs1b + (size_t)2 * n * 32;             // 2 slabs x n x 32 bf16
    int* bcur    = (int*)(hs2b + (size_t)2 * n * 32);     // nb
    int* rp2     = bcur + ((nb + 1) & ~1);                // 2n ints (int2/node)
    ushort* csr  = (ushort*)(rp2 + 2 * (size_t)n);        // nb*CAP ushorts
    float* gagg  = (float*)(csr + (size_t)nb * CAP);      // n*64 fp32
    int* binbuf  = (int*)(gagg + (size_t)n * 64);         // nb*CAP ints
    float* out   = (float*)d_out;

    int chunk = (e + NTILE - 1) / NTILE;
    int pg = (n + 63) / 64;                 // node-blocks per slab
    int pgrid = 8 * ((pg + 3) / 4);         // XCD-pinned 2-slab grid

    dim3 blk(256);
    k_init<<<(nb + 255) / 256, blk, 0, stream>>>(bcur, nb);
    k_tilesort<<<NTILE, blk, 0, stream>>>(row, col, bcur, binbuf, e, chunk);
    k_build<<<nb, blk, 0, stream>>>(binbuf, bcur, dis, rp2, csr, n);
    k_gemm1<<<(n + 63) / 64, blk, 0, stream>>>(x, W1, dis, hs1b, n);
    k_pull1<<<pgrid, blk, 0, stream>>>(rp2, csr, hs1b, dis, b1, hs2b, n);
    k_pull2<<<pgrid, blk, 0, stream>>>(rp2, csr, hs2b, dis, gagg, n);
    k_gemm23<<<(n + 63) / 64, blk, 0, stream>>>(gagg, W2, b2, W3, b3, out, n);
}

// Round 14
// 153.029 us; speedup vs baseline: 2.8399x; 1.0389x over previous
//
#include <hip/hip_runtime.h>

// GCN VGAE encoder, pull-based. N=50000 (<2^16), E=1.6M.
// out[i] = dis[i]*(hs[i]+sum_{j->i} hs[j]), hs = dis.*(x@W)
// Round 14: pulls unroll 8 (deeper L2-gather pipeline; round 8 showed
// latency-bound at VALUBusy 9%); tilesort caches its edge chunk in LDS.
// Kept: fixed-cap buckets (CAP=16384) + gapped CSR int2 extents (round 13);
// separate dispatches (round 12: grid.sync ~100us each — never fuse);
// bf16 32-ch slabs, XCD-pinned merged pulls (rounds 9/11); bounded unrolls
// (round 7: full unroll spilled); no hipMemsetAsync (round 10).

#define NBMAX 256
#define NTILE 512
#define CAPSH 14
#define CAP (1 << CAPSH)
#define TSCACHE 3264

__device__ __forceinline__ ushort f2bf(float x) {            // RNE fp32->bf16
    unsigned u = __float_as_uint(x);
    u = (u + 0x7FFFu + ((u >> 16) & 1u)) >> 16;
    return (ushort)u;
}
__device__ __forceinline__ float bflo(unsigned u) { return __uint_as_float(u << 16); }
__device__ __forceinline__ float bfhi(unsigned u) { return __uint_as_float(u & 0xFFFF0000u); }

__device__ __forceinline__ void acc8(float* a, uint4 x) {    // a[0..7] += 8 bf16
    a[0] += bflo(x.x); a[1] += bfhi(x.x);
    a[2] += bflo(x.y); a[3] += bfhi(x.y);
    a[4] += bflo(x.z); a[5] += bfhi(x.z);
    a[6] += bflo(x.w); a[7] += bfhi(x.w);
}

__global__ void k_init(int* __restrict__ bcur, int nb) {
    int i = blockIdx.x * 256 + threadIdx.x;
    if (i < nb) bcur[i] = i << CAPSH;
}

// tilesort into fixed-cap bucket regions (packed row | lcol<<16).
// Edge chunk cached in LDS during histogram pass; scatter reads LDS.
__global__ __launch_bounds__(256) void k_tilesort(const int* __restrict__ row,
                                                  const int* __restrict__ col,
                                                  int* __restrict__ bcur,
                                                  int* __restrict__ binbuf,
                                                  int e, int chunk) {
    __shared__ int lh[NBMAX];
    __shared__ int2 ec[TSCACHE];
    int t0 = blockIdx.x * chunk;
    int t1 = t0 + chunk < e ? t0 + chunk : e;
    int cnt = t1 - t0;
    for (int i = threadIdx.x; i < NBMAX; i += 256) lh[i] = 0;
    __syncthreads();
    if (cnt <= TSCACHE) {
        for (int i = threadIdx.x; i < cnt; i += 256) {
            int2 rc = make_int2(row[t0 + i], col[t0 + i]);
            ec[i] = rc;
            atomicAdd(&lh[rc.y >> 8], 1);
        }
        __syncthreads();
        for (int b = threadIdx.x; b < NBMAX; b += 256) {
            int c = lh[b];
            if (c) lh[b] = atomicAdd(bcur + b, c);
        }
        __syncthreads();
        for (int i = threadIdx.x; i < cnt; i += 256) {
            int2 rc = ec[i];
            int pos = atomicAdd(&lh[rc.y >> 8], 1);
            if (pos < (((rc.y >> 8) + 1) << CAPSH))   // overflow guard
                binbuf[pos] = rc.x | ((rc.y & 255) << 16);
        }
    } else {                                           // generic fallback
        for (int i = t0 + threadIdx.x; i < t1; i += 256)
            atomicAdd(&lh[col[i] >> 8], 1);
        __syncthreads();
        for (int b = threadIdx.x; b < NBMAX; b += 256) {
            int c = lh[b];
            if (c) lh[b] = atomicAdd(bcur + b, c);
        }
        __syncthreads();
        for (int i = t0 + threadIdx.x; i < t1; i += 256) {
            int c = col[i];
            int pos = atomicAdd(&lh[c >> 8], 1);
            if (pos < (((c >> 8) + 1) << CAPSH))
                binbuf[pos] = row[i] | ((c & 255) << 16);
        }
    }
}

// per bucket: counts -> prefix -> rp2/dis, scatter csr (gapped CSR)
__global__ __launch_bounds__(256) void k_build(const int* __restrict__ binbuf,
                                               const int* __restrict__ bcur,
                                               float* __restrict__ dis,
                                               int* __restrict__ rp2,
                                               ushort* __restrict__ csr, int n) {
    __shared__ int lcnt[256], s[256], cur[256];
    int b = blockIdx.x;
    int t = threadIdx.x;
    int lo = b << CAPSH;
    int hi = bcur[b];
    int cap = (b + 1) << CAPSH;
    if (hi > cap) hi = cap;
    int node0 = b << 8;
    int nloc = n - node0 < 256 ? n - node0 : 256;
    lcnt[t] = 0;
    __syncthreads();
    for (int k = lo + t; k < hi; k += 256)
        atomicAdd(&lcnt[(binbuf[k] >> 16) & 255], 1);
    __syncthreads();
    int v = lcnt[t];
    s[t] = v;
    __syncthreads();
    for (int off = 1; off < 256; off <<= 1) {
        int u = (t >= off) ? s[t - off] : 0;
        __syncthreads();
        s[t] += u;
        __syncthreads();
    }
    if (t < nloc) {
        int beg = lo + s[t] - v;
        rp2[2 * (node0 + t)] = beg;
        rp2[2 * (node0 + t) + 1] = beg + v;
        cur[t] = beg;
        dis[node0 + t] = rsqrtf((float)v + 1.0f);
    }
    __syncthreads();
    for (int k = lo + t; k < hi; k += 256) {
        int p = binbuf[k];
        int pos = atomicAdd(&cur[(p >> 16) & 255], 1);
        csr[pos] = (ushort)(p & 0xffff);
    }
}

// x[n,128] @ W[128,64] * dis -> bf16 slabs hs1b[2][n][32]. 64 rows/block.
// W in LDS as [k4][ch] float4 (32KB); x staged per wave in 4 K-stages (8KB).
__global__ __launch_bounds__(256) void k_gemm1(const float* __restrict__ x,
                                               const float* __restrict__ W,
                                               const float* __restrict__ dis,
                                               ushort* __restrict__ hs1b, int n) {
    __shared__ float4 w4[32][64];          // [k4][ch]
    __shared__ float4 xs[4][16][8];        // [wave][row][k4local]
    for (int i = threadIdx.x; i < 128 * 64; i += 256) {
        int k = i >> 6, c = i & 63;
        ((float*)&w4[k >> 2][c])[k & 3] = W[i];
    }
    int wid = threadIdx.x >> 6;
    int lane = threadIdx.x & 63;
    int r0 = blockIdx.x * 64 + wid * 16;
    const float4* x4 = (const float4*)x;
    float acc[16];
#pragma unroll
    for (int r = 0; r < 16; ++r) acc[r] = 0.f;
    __syncthreads();
#pragma unroll
    for (int st = 0; st < 4; ++st) {
#pragma unroll
        for (int j = 0; j < 2; ++j) {
            int idx = j * 64 + lane;       // (rowl, k4l) = (idx>>3, idx&7)
            int rr = r0 + (idx >> 3);
            if (rr >= n) rr = n - 1;
            xs[wid][idx >> 3][idx & 7] = x4[(size_t)rr * 32 + st * 8 + (idx & 7)];
        }
        // xs[wid] is wave-private: in-wave lgkmcnt ordering suffices
#pragma unroll 2
        for (int k4 = 0; k4 < 8; ++k4) {
            float4 wv = w4[st * 8 + k4][lane];
#pragma unroll
            for (int r = 0; r < 16; ++r) {
                float4 xv = xs[wid][r][k4];
                acc[r] = fmaf(xv.x, wv.x, acc[r]);
                acc[r] = fmaf(xv.y, wv.y, acc[r]);
                acc[r] = fmaf(xv.z, wv.z, acc[r]);
                acc[r] = fmaf(xv.w, wv.w, acc[r]);
            }
        }
    }
    ushort* hb = hs1b + (size_t)(lane >> 5) * n * 32 + (lane & 31);
#pragma unroll
    for (int r = 0; r < 16; ++r) {
        int rw = r0 + r;
        if (rw < n) hb[(size_t)rw * 32] = f2bf(dis[rw] * acc[r]);
    }
}

// pull1, both slabs in one dispatch; xcd=bid&7 picks slab (xcd>>2) so each
// XCD's L2 caches one 3.2MB slab. 4 lanes/node, uint4 (8 bf16)/lane.
// 8-deep gather unroll: latency-bound (round 8: VALUBusy 9%).
__global__ __launch_bounds__(256) void k_pull1(const int* __restrict__ rp2,
                                               const ushort* __restrict__ csr,
                                               const ushort* __restrict__ hs1b,
                                               const float* __restrict__ dis,
                                               const float* __restrict__ b1,
                                               ushort* __restrict__ hs2b, int n) {
    int xcd = blockIdx.x & 7;
    int sid = xcd >> 2;
    int idx = (blockIdx.x >> 3) * 4 + (xcd & 3);
    int node = idx * 64 + (threadIdx.x >> 2);
    int c4 = threadIdx.x & 3;
    if (node >= n) return;
    size_t slab = (size_t)sid * n * 32;
    const uint4* h4 = (const uint4*)(hs1b + slab);
    int2 be = ((const int2*)rp2)[node];
    float a[8], b[8];
    uint4 v = h4[(size_t)node * 4 + c4];
    a[0] = bflo(v.x); a[1] = bfhi(v.x); a[2] = bflo(v.y); a[3] = bfhi(v.y);
    a[4] = bflo(v.z); a[5] = bfhi(v.z); a[6] = bflo(v.w); a[7] = bfhi(v.w);
#pragma unroll
    for (int j = 0; j < 8; ++j) b[j] = 0.f;
    int k = be.x;
    for (; k + 8 <= be.y; k += 8) {
        uint4 v0 = h4[(size_t)csr[k] * 4 + c4];
        uint4 v1 = h4[(size_t)csr[k + 1] * 4 + c4];
        uint4 v2 = h4[(size_t)csr[k + 2] * 4 + c4];
        uint4 v3 = h4[(size_t)csr[k + 3] * 4 + c4];
        uint4 v4 = h4[(size_t)csr[k + 4] * 4 + c4];
        uint4 v5 = h4[(size_t)csr[k + 5] * 4 + c4];
        uint4 v6 = h4[(size_t)csr[k + 6] * 4 + c4];
        uint4 v7 = h4[(size_t)csr[k + 7] * 4 + c4];
        acc8(a, v0); acc8(b, v1); acc8(a, v2); acc8(b, v3);
        acc8(a, v4); acc8(b, v5); acc8(a, v6); acc8(b, v7);
    }
    if (k + 4 <= be.y) {
        uint4 v0 = h4[(size_t)csr[k] * 4 + c4];
        uint4 v1 = h4[(size_t)csr[k + 1] * 4 + c4];
        uint4 v2 = h4[(size_t)csr[k + 2] * 4 + c4];
        uint4 v3 = h4[(size_t)csr[k + 3] * 4 + c4];
        acc8(a, v0); acc8(b, v1); acc8(a, v2); acc8(b, v3);
        k += 4;
    }
    for (; k < be.y; ++k) acc8(a, h4[(size_t)csr[k] * 4 + c4]);
    float d = dis[node];
    const float* b1s = b1 + sid * 32;
    float4 bb0 = *(const float4*)(b1s + c4 * 8);
    float4 bb1 = *(const float4*)(b1s + c4 * 8 + 4);
    float bj[8] = {bb0.x, bb0.y, bb0.z, bb0.w, bb1.x, bb1.y, bb1.z, bb1.w};
    float o[8];
#pragma unroll
    for (int j = 0; j < 8; ++j) {
        float tt = fmaf(d, a[j] + b[j], bj[j]);
        o[j] = tt > 0.f ? d * tt : 0.f;
    }
    uint4 w;
    w.x = (unsigned)f2bf(o[0]) | ((unsigned)f2bf(o[1]) << 16);
    w.y = (unsigned)f2bf(o[2]) | ((unsigned)f2bf(o[3]) << 16);
    w.z = (unsigned)f2bf(o[4]) | ((unsigned)f2bf(o[5]) << 16);
    w.w = (unsigned)f2bf(o[6]) | ((unsigned)f2bf(o[7]) << 16);
    ((uint4*)(hs2b + slab))[(size_t)node * 4 + c4] = w;
}

// pull2, both slabs in one dispatch (same XCD-pinned mapping). fp32 out.
__global__ __launch_bounds__(256) void k_pull2(const int* __restrict__ rp2,
                                               const ushort* __restrict__ csr,
                                               const ushort* __restrict__ hs2b,
                                               const float* __restrict__ dis,
                                               float* __restrict__ gagg, int n) {
    int xcd = blockIdx.x & 7;
    int sid = xcd >> 2;
    int idx = (blockIdx.x >> 3) * 4 + (xcd & 3);
    int node = idx * 64 + (threadIdx.x >> 2);
    int c4 = threadIdx.x & 3;
    if (node >= n) return;
    const uint4* h4 = (const uint4*)(hs2b + (size_t)sid * n * 32);
    int2 be = ((const int2*)rp2)[node];
    float a[8], b[8];
    uint4 v = h4[(size_t)node * 4 + c4];
    a[0] = bflo(v.x); a[1] = bfhi(v.x); a[2] = bflo(v.y); a[3] = bfhi(v.y);
    a[4] = bflo(v.z); a[5] = bfhi(v.z); a[6] = bflo(v.w); a[7] = bfhi(v.w);
#pragma unroll
    for (int j = 0; j < 8; ++j) b[j] = 0.f;
    int k = be.x;
    for (; k + 8 <= be.y; k += 8) {
        uint4 v0 = h4[(size_t)csr[k] * 4 + c4];
        uint4 v1 = h4[(size_t)csr[k + 1] * 4 + c4];
        uint4 v2 = h4[(size_t)csr[k + 2] * 4 + c4];
        uint4 v3 = h4[(size_t)csr[k + 3] * 4 + c4];
        uint4 v4 = h4[(size_t)csr[k + 4] * 4 + c4];
        uint4 v5 = h4[(size_t)csr[k + 5] * 4 + c4];
        uint4 v6 = h4[(size_t)csr[k + 6] * 4 + c4];
        uint4 v7 = h4[(size_t)csr[k + 7] * 4 + c4];
        acc8(a, v0); acc8(b, v1); acc8(a, v2); acc8(b, v3);
        acc8(a, v4); acc8(b, v5); acc8(a, v6); acc8(b, v7);
    }
    if (k + 4 <= be.y) {
        uint4 v0 = h4[(size_t)csr[k] * 4 + c4];
        uint4 v1 = h4[(size_t)csr[k + 1] * 4 + c4];
        uint4 v2 = h4[(size_t)csr[k + 2] * 4 + c4];
        uint4 v3 = h4[(size_t)csr[k + 3] * 4 + c4];
        acc8(a, v0); acc8(b, v1); acc8(a, v2); acc8(b, v3);
        k += 4;
    }
    for (; k < be.y; ++k) acc8(a, h4[(size_t)csr[k] * 4 + c4]);
    float d = dis[node];
    float* dst = gagg + (size_t)node * 64 + sid * 32 + c4 * 8;
    *(float4*)dst = make_float4(d * (a[0] + b[0]), d * (a[1] + b[1]),
                                d * (a[2] + b[2]), d * (a[3] + b[3]));
    *(float4*)(dst + 4) = make_float4(d * (a[4] + b[4]), d * (a[5] + b[5]),
                                      d * (a[6] + b[6]), d * (a[7] + b[7]));
}

// g[n,64] @ {W2,W3}[64,32] + bias -> out = mu ++ logvar. 64 rows/block.
__global__ __launch_bounds__(256) void k_gemm23(const float* __restrict__ g,
                                                const float* __restrict__ W2,
                                                const float* __restrict__ b2,
                                                const float* __restrict__ W3,
                                                const float* __restrict__ b3,
                                                float* __restrict__ out, int n) {
    __shared__ float ws[2 * 32 * 17 * 4];  // [half][ch][k4] float4, stride 17
    __shared__ float4 gs[4][16 * 16];      // per-wave 16 rows x 16 float4
    for (int i = threadIdx.x; i < 64 * 32; i += 256) {
        int k = i >> 5, c = i & 31;
        int a = (c * 17 + (k >> 2)) * 4 + (k & 3);
        ws[a] = W2[i];
        ws[2176 + a] = W3[i];
    }
    int wid = threadIdx.x >> 6;
    int lane = threadIdx.x & 63;
    int half = lane >> 5;
    int ch = lane & 31;
    int r0 = blockIdx.x * 64 + wid * 16;
    const float4* g4 = (const float4*)g;
#pragma unroll
    for (int j = 0; j < 4; ++j) {
        int idx = j * 64 + lane;           // (row, k4) = (idx>>4, idx&15)
        int rr = r0 + (idx >> 4);
        if (rr >= n) rr = n - 1;
        gs[wid][idx] = g4[(size_t)rr * 16 + (idx & 15)];
    }
    __syncthreads();
    float acc[16];
#pragma unroll
    for (int r = 0; r < 16; ++r) acc[r] = 0.f;
    const float4* wl = (const float4*)ws;
    const float4* gw = gs[wid];
#pragma unroll 2
    for (int k4 = 0; k4 < 16; ++k4) {
        float4 wv = wl[half * 544 + ch * 17 + k4];
#pragma unroll
        for (int r = 0; r < 16; ++r) {
            float4 gv = gw[r * 16 + k4];   // wave-uniform -> LDS broadcast
            acc[r] = fmaf(gv.x, wv.x, acc[r]);
            acc[r] = fmaf(gv.y, wv.y, acc[r]);
            acc[r] = fmaf(gv.z, wv.z, acc[r]);
            acc[r] = fmaf(gv.w, wv.w, acc[r]);
        }
    }
    float bb = half ? b3[ch] : b2[ch];
    size_t obase = half ? (size_t)n * 32 : 0;
#pragma unroll
    for (int r = 0; r < 16; ++r) {
        int rw = r0 + r;
        if (rw < n) out[obase + (size_t)rw * 32 + ch] = acc[r] + bb;
    }
}

extern "C" void kernel_launch(void* const* d_in, const int* in_sizes, int n_in,
                              void* d_out, int out_size, void* d_ws, size_t ws_size,
                              hipStream_t stream) {
    const float* x  = (const float*)d_in[0];
    const int*   ei = (const int*)d_in[1];
    const float* W1 = (const float*)d_in[2];
    const float* b1 = (const float*)d_in[3];
    const float* W2 = (const float*)d_in[4];
    const float* b2 = (const float*)d_in[5];
    const float* W3 = (const float*)d_in[6];
    const float* b3 = (const float*)d_in[7];

    int n = in_sizes[0] / 128;   // 50000
    int e = in_sizes[1] / 2;     // 1600000
    int nb = (n + 255) >> 8;     // 196 buckets of 256 nodes
    const int* row = ei;
    const int* col = ei + e;

    // ws layout: dis 0.2M | hs1b 6.4M | hs2b 6.4M | bcur | rp2 0.4M |
    // csr 6.4M | gagg 12.8M | binbuf 12.85M   (~45.5MB total)
    float* fws   = (float*)d_ws;
    float* dis   = fws;                                   // n fp32
    ushort* hs1b = (ushort*)(fws + n);                    // 2 slabs x n x 32 bf16
    ushort* hs2b = hs1b + (size_t)2 * n * 32;             // 2 slabs x n x 32 bf16
    int* bcur    = (int*)(hs2b + (size_t)2 * n * 32);     // nb
    int* rp2     = bcur + ((nb + 1) & ~1);                // 2n ints (int2/node)
    ushort* csr  = (ushort*)(rp2 + 2 * (size_t)n);        // nb*CAP ushorts
    float* gagg  = (float*)(csr + (size_t)nb * CAP);      // n*64 fp32
    int* binbuf  = (int*)(gagg + (size_t)n * 64);         // nb*CAP ints
    float* out   = (float*)d_out;

    int chunk = (e + NTILE - 1) / NTILE;
    int pg = (n + 63) / 64;                 // node-blocks per slab
    int pgrid = 8 * ((pg + 3) / 4);         // XCD-pinned 2-slab grid

    dim3 blk(256);
    k_init<<<(nb + 255) / 256, blk, 0, stream>>>(bcur, nb);
    k_tilesort<<<NTILE, blk, 0, stream>>>(row, col, bcur, binbuf, e, chunk);
    k_build<<<nb, blk, 0, stream>>>(binbuf, bcur, dis, rp2, csr, n);
    k_gemm1<<<(n + 63) / 64, blk, 0, stream>>>(x, W1, dis, hs1b, n);
    k_pull1<<<pgrid, blk, 0, stream>>>(rp2, csr, hs1b, dis, b1, hs2b, n);
    k_pull2<<<pgrid, blk, 0, stream>>>(rp2, csr, hs2b, dis, gagg, n);
    k_gemm23<<<(n + 63) / 64, blk, 0, stream>>>(gagg, W2, b2, W3, b3, out, n);
}